// Round 8
// baseline (761.599 us; speedup 1.0000x reference)
//
#include <hip/hip_runtime.h>
#include <hip/hip_bf16.h>
#include <cstdint>

#define ND 128
#define ROWS 32   // tile rows (was 64): halves LDS -> 8 blocks/CU residency
#define NT 256    // threads per block (4 waves)
#define LDA 136   // padded LDS row stride (f16 elems)
#define LDM 130   // padded LDS row stride for f32 message tile

typedef _Float16 f16x8 __attribute__((ext_vector_type(8)));
typedef _Float16 f16x4 __attribute__((ext_vector_type(4)));
typedef float    f32x4 __attribute__((ext_vector_type(4)));

// tanh-approx GELU: gelu(v) = v*e/(e+1), e = exp2(2.302118131*v*(1+0.044715 v^2))
__device__ __forceinline__ float gelu_fast(float v) {
    float w = v * v;
    float u = v * fmaf(w, 0.044715f, 1.0f);
    float t = fminf(u * 2.302118131f, 126.0f);   // clamp: avoid inf/inf -> NaN
    float e = __builtin_amdgcn_exp2f(t);
    return v * e * __builtin_amdgcn_rcpf(e + 1.0f);
}

__device__ __forceinline__ uint32_t pkrtz_u32(float a, float b) {
    return __builtin_bit_cast(uint32_t, __builtin_amdgcn_cvt_pkrtz(a, b));
}

// Transpose + cast the four 128x128 f32 weight matrices to f16 Wt[col][k].
__global__ void prep_weights(const float* __restrict__ w0, const float* __restrict__ w1,
                             const float* __restrict__ w2, const float* __restrict__ w3,
                             _Float16* __restrict__ wt) {
    int id = blockIdx.x * blockDim.x + threadIdx.x;   // 0..65535
    int m   = id >> 14;
    int idx = id & 16383;
    int c = idx >> 7, k = idx & 127;
    const float* W = (m == 0) ? w0 : (m == 1) ? w1 : (m == 2) ? w2 : w3;
    wt[(m << 14) + (c << 7) + k] = (_Float16)W[(k << 7) + c];
}

__global__ void hist_kernel(const int* __restrict__ dst, int* __restrict__ cnt, int E) {
    int e = blockIdx.x * blockDim.x + threadIdx.x;
    if (e < E) atomicAdd(&cnt[dst[e]], 1);
}

// pass 1: per-1024-chunk exclusive scan (in place) + chunk totals
__global__ void scan_pass1(int* __restrict__ data, int* __restrict__ bsum, int n) {
    __shared__ int wsum[16];
    const int t = threadIdx.x, lane = t & 63, wv = t >> 6;
    int i = blockIdx.x * 1024 + t;
    int v = (i < n) ? data[i] : 0;
    int s = v;
    #pragma unroll
    for (int off = 1; off < 64; off <<= 1) {
        int u = __shfl_up(s, off, 64);
        if (lane >= off) s += u;
    }
    if (lane == 63) wsum[wv] = s;
    __syncthreads();
    if (t == 0) {
        int run = 0;
        #pragma unroll
        for (int w = 0; w < 16; ++w) { int x = wsum[w]; wsum[w] = run; run += x; }
        bsum[blockIdx.x] = run;
    }
    __syncthreads();
    if (i < n) data[i] = s - v + wsum[wv];
}

// pass 2: exclusive scan of chunk totals (1 block, nb <= 1024)
__global__ void scan_pass2(int* __restrict__ bsum, int nb) {
    __shared__ int wsum[16];
    const int t = threadIdx.x, lane = t & 63, wv = t >> 6;
    int v = (t < nb) ? bsum[t] : 0;
    int s = v;
    #pragma unroll
    for (int off = 1; off < 64; off <<= 1) {
        int u = __shfl_up(s, off, 64);
        if (lane >= off) s += u;
    }
    if (lane == 63) wsum[wv] = s;
    __syncthreads();
    if (t == 0) {
        int run = 0;
        #pragma unroll
        for (int w = 0; w < 16; ++w) { int x = wsum[w]; wsum[w] = run; run += x; }
    }
    __syncthreads();
    if (t < nb) bsum[t] = s - v + wsum[wv];
}

// pass 3: add chunk offsets
__global__ void scan_pass3(int* __restrict__ data, const int* __restrict__ bsum, int n) {
    int i = blockIdx.x * 1024 + threadIdx.x;
    if (i < n && blockIdx.x > 0) data[i] += bsum[blockIdx.x];
}

__global__ void scatter_kernel(const int* __restrict__ dst, int* __restrict__ cur,
                               int* __restrict__ perm, int E) {
    int e = blockIdx.x * blockDim.x + threadIdx.x;
    if (e < E) {
        int p = atomicAdd(&cur[dst[e]], 1);
        perm[p] = e;
    }
}

// Fused row-MLP: out_row = (GELU(in_row @ W1 + b1)) @ W2 + b2
// 256 threads = 4 waves; each wave owns 32 rows x 32 cols (2x2 16x16 frags).
template<bool EDGE, bool SORTED>
__global__ __launch_bounds__(NT, 8) void mlp_fused(
    const float* __restrict__ xp,
    const float* __restrict__ rowin,     // EDGE: edge_attr ; else agg
    const int*   __restrict__ srcp,
    const int*   __restrict__ dstp,
    const int*   __restrict__ permp,
    const _Float16* __restrict__ wt1,    // [128 cols][128 k] f16 (transposed)
    const _Float16* __restrict__ wt2,
    const float* __restrict__ b1p,
    const float* __restrict__ b2p,
    const float* __restrict__ epsp,
    float* __restrict__ outp,            // EDGE: agg (atomic) ; else out
    int nRows, int nTiles)
{
    // A (8704 B) | H (8704 B); M (16640 B f32) aliases A+H (SORTED only)
    __shared__ __align__(16) char lds_raw[ROWS * LDA * 2 * sizeof(_Float16)];
    __shared__ int dtile[ROWS];
    _Float16* Abuf = (_Float16*)lds_raw;
    _Float16* Hbuf = (_Float16*)(lds_raw + ROWS * LDA * sizeof(_Float16));
    float*    Mbuf = (float*)lds_raw;

    const int tid  = threadIdx.x;
    const int lane = tid & 63;
    const int wc   = tid >> 6;   // 4 waves: each owns a 32-col group
    const int l15  = lane & 15;
    const int khi  = lane >> 4;  // 0..3

    // persistent weight fragments: 32 VGPR each
    f16x8 wf1[2][4], wf2[2][4];
    float bb1[2], bb2[2];
    #pragma unroll
    for (int ct = 0; ct < 2; ++ct) {
        int col = wc * 32 + ct * 16 + l15;
        #pragma unroll
        for (int kk = 0; kk < 4; ++kk) {
            wf1[ct][kk] = *(const f16x8*)(wt1 + col * ND + kk * 32 + khi * 8);
            wf2[ct][kk] = *(const f16x8*)(wt2 + col * ND + kk * 32 + khi * 8);
        }
        bb1[ct] = b1p[col];
        bb2[ct] = b2p[col];
    }

    float scale = 1.0f;
    if (!EDGE) scale = 1.0f + epsp[0];

    const int sr = tid >> 3;        // staging row 0..31
    const int sc = (tid & 7) * 4;   // staging col base; +i*32 per iter

    for (int tile = blockIdx.x; tile < nTiles; tile += gridDim.x) {
        const int base = tile * ROWS;

        // ---- stage A tile (f32 -> f16 via pkrtz, fused gather/add) + dtile ----
        {
            int grow = base + sr;
            if (grow < nRows) {
                int prow = grow;
                if (EDGE && SORTED) prow = permp[grow];
                if (EDGE && SORTED && (tid & 7) == 0) dtile[sr] = dstp[prow];
                const float* er = rowin + (size_t)prow * ND;
                const float* xr;
                if (EDGE) xr = xp + (size_t)srcp[prow] * ND;
                else      xr = xp + (size_t)grow * ND;
                #pragma unroll
                for (int i = 0; i < 4; ++i) {
                    int c = sc + i * 32;
                    float4 a = *(const float4*)(er + c);
                    float4 b = *(const float4*)(xr + c);
                    float s0, s1, s2, s3;
                    if (EDGE) {
                        s0 = a.x + b.x; s1 = a.y + b.y; s2 = a.z + b.z; s3 = a.w + b.w;
                    } else {
                        s0 = fmaf(scale, b.x, a.x); s1 = fmaf(scale, b.y, a.y);
                        s2 = fmaf(scale, b.z, a.z); s3 = fmaf(scale, b.w, a.w);
                    }
                    uint2 v;
                    v.x = pkrtz_u32(s0, s1);
                    v.y = pkrtz_u32(s2, s3);
                    *(uint2*)&Abuf[sr * LDA + c] = v;
                }
            } else {
                if (EDGE && SORTED && (tid & 7) == 0) dtile[sr] = -1;
                #pragma unroll
                for (int i = 0; i < 4; ++i) {
                    uint2 z = {0u, 0u};
                    *(uint2*)&Abuf[sr * LDA + sc + i * 32] = z;
                }
            }
        }

        __syncthreads();   // S1: Abuf+dtile ready; prev tile LDS readers done

        // ---- GEMM1: h = A @ W1 ----
        f32x4 acc[2][2];
        #pragma unroll
        for (int rt = 0; rt < 2; ++rt)
            #pragma unroll
            for (int ct = 0; ct < 2; ++ct)
                acc[rt][ct] = (f32x4)0.0f;

        #pragma unroll
        for (int kk = 0; kk < 4; ++kk) {
            f16x8 af[2];
            #pragma unroll
            for (int rt = 0; rt < 2; ++rt)
                af[rt] = *(const f16x8*)&Abuf[(rt * 16 + l15) * LDA + kk * 32 + khi * 8];
            #pragma unroll
            for (int rt = 0; rt < 2; ++rt)
                #pragma unroll
                for (int ct = 0; ct < 2; ++ct)
                    acc[rt][ct] = __builtin_amdgcn_mfma_f32_16x16x32_f16(
                        af[rt], wf1[ct][kk], acc[rt][ct], 0, 0, 0);
        }

        // ---- epilogue 1: bias + GELU -> Hbuf (f16) ----
        #pragma unroll
        for (int rt = 0; rt < 2; ++rt)
            #pragma unroll
            for (int ct = 0; ct < 2; ++ct) {
                int col = wc * 32 + ct * 16 + l15;
                #pragma unroll
                for (int q = 0; q < 4; ++q) {
                    int rl = rt * 16 + khi * 4 + q;
                    Hbuf[rl * LDA + col] = (_Float16)gelu_fast(acc[rt][ct][q] + bb1[ct]);
                }
            }

        __syncthreads();   // S2: Hbuf ready

        // ---- GEMM2: m = H @ W2 ----
        f32x4 acc2[2][2];
        #pragma unroll
        for (int rt = 0; rt < 2; ++rt)
            #pragma unroll
            for (int ct = 0; ct < 2; ++ct)
                acc2[rt][ct] = (f32x4)0.0f;

        #pragma unroll
        for (int kk = 0; kk < 4; ++kk) {
            f16x8 hf[2];
            #pragma unroll
            for (int rt = 0; rt < 2; ++rt)
                hf[rt] = *(const f16x8*)&Hbuf[(rt * 16 + l15) * LDA + kk * 32 + khi * 8];
            #pragma unroll
            for (int rt = 0; rt < 2; ++rt)
                #pragma unroll
                for (int ct = 0; ct < 2; ++ct)
                    acc2[rt][ct] = __builtin_amdgcn_mfma_f32_16x16x32_f16(
                        hf[rt], wf2[ct][kk], acc2[rt][ct], 0, 0, 0);
        }

        if (EDGE && SORTED) {
            __syncthreads();   // S3: Hbuf reads done before Mbuf (alias) writes

            // ---- epilogue 2s: bias -> Mbuf (f32) ----
            #pragma unroll
            for (int rt = 0; rt < 2; ++rt)
                #pragma unroll
                for (int ct = 0; ct < 2; ++ct) {
                    int col = wc * 32 + ct * 16 + l15;
                    #pragma unroll
                    for (int q = 0; q < 4; ++q) {
                        int rl = rt * 16 + khi * 4 + q;
                        Mbuf[rl * LDM + col] = acc2[rt][ct][q] + bb2[ct];
                    }
                }

            __syncthreads();   // S4: Mbuf ready

            // ---- segmented reduce over dst-sorted rows (2 groups of 16) ----
            const int rc = tid & 127;   // column
            const int rg = tid >> 7;    // 0..1 : 16-row group
            float a = 0.0f;
            #pragma unroll
            for (int r = rg * 16; r < rg * 16 + 16; ++r) {
                int d = dtile[r];
                if (d >= 0) {
                    a += Mbuf[r * LDM + rc];
                    if (r == rg * 16 + 15 || dtile[r + 1] != d) {
                        atomicAdd(outp + (size_t)d * ND + rc, a);
                        a = 0.0f;
                    }
                }
            }

            __syncthreads();   // S5: Mbuf/dtile reads done before next stage
        } else {
            // ---- epilogue 2: bias + scatter(atomic) or store ----
            #pragma unroll
            for (int rt = 0; rt < 2; ++rt)
                #pragma unroll
                for (int ct = 0; ct < 2; ++ct) {
                    int col = wc * 32 + ct * 16 + l15;
                    #pragma unroll
                    for (int q = 0; q < 4; ++q) {
                        int rl = rt * 16 + khi * 4 + q;
                        int grow = base + rl;
                        if (grow < nRows) {
                            float v = acc2[rt][ct][q] + bb2[ct];
                            if (EDGE) {
                                int d = dstp[grow];
                                atomicAdd(outp + (size_t)d * ND + col, v);
                            } else {
                                outp[(size_t)grow * ND + col] = v;
                            }
                        }
                    }
                }
        }
    }
}

extern "C" void kernel_launch(void* const* d_in, const int* in_sizes, int n_in,
                              void* d_out, int out_size, void* d_ws, size_t ws_size,
                              hipStream_t stream)
{
    const float* x   = (const float*)d_in[0];
    const int*   ei  = (const int*)d_in[1];    // [2,E] int32: row0=src, row1=dst
    const float* ea  = (const float*)d_in[2];
    const float* We1 = (const float*)d_in[3];
    const float* be1 = (const float*)d_in[4];
    const float* We2 = (const float*)d_in[5];
    const float* be2 = (const float*)d_in[6];
    const float* Wu1 = (const float*)d_in[7];
    const float* bu1 = (const float*)d_in[8];
    const float* Wu2 = (const float*)d_in[9];
    const float* bu2 = (const float*)d_in[10];
    const float* eps = (const float*)d_in[11];

    const int E  = in_sizes[1] / 2;    // 600000
    const int Nn = in_sizes[0] / ND;   // 50000

    const size_t aggB = (size_t)Nn * ND * sizeof(float);      // 25.6 MB
    const size_t cntB = ((size_t)Nn * sizeof(int) + 255) & ~(size_t)255;
    const size_t prmB = (size_t)E * sizeof(int);
    const size_t bsmB = 4096;
    const size_t wtB  = 4 * 16384 * sizeof(_Float16);
    const bool sorted = (ws_size >= aggB + cntB + prmB + bsmB + wtB);

    float* agg = (float*)d_ws;
    const int tilesE = (E + ROWS - 1) / ROWS;
    const int tilesN = (Nn + ROWS - 1) / ROWS;
    const int gridE  = (tilesE < 2048) ? tilesE : 2048;   // = resident set (8 blk/CU)
    const int gridN  = (tilesN < 2048) ? tilesN : 2048;

    if (sorted) {
        int*      cnt  = (int*)((char*)d_ws + aggB);
        int*      perm = (int*)((char*)d_ws + aggB + cntB);
        int*      bsum = (int*)((char*)d_ws + aggB + cntB + prmB);
        _Float16* wt   = (_Float16*)((char*)d_ws + aggB + cntB + prmB + bsmB);

        (void)hipMemsetAsync(d_ws, 0, aggB + cntB, stream);   // zero agg + counts
        prep_weights<<<dim3(256), dim3(256), 0, stream>>>(We1, We2, Wu1, Wu2, wt);

        const int gE = (E + 511) / 512;
        const int nb = (Nn + 1023) / 1024;
        hist_kernel<<<dim3(gE), dim3(512), 0, stream>>>(ei + E, cnt, E);
        scan_pass1<<<dim3(nb), dim3(1024), 0, stream>>>(cnt, bsum, Nn);
        scan_pass2<<<dim3(1), dim3(1024), 0, stream>>>(bsum, nb);
        scan_pass3<<<dim3(nb), dim3(1024), 0, stream>>>(cnt, bsum, Nn);
        scatter_kernel<<<dim3(gE), dim3(512), 0, stream>>>(ei + E, cnt, perm, E);

        mlp_fused<true, true><<<dim3(gridE), dim3(NT), 0, stream>>>(
            x, ea, ei, ei + E, perm, wt, wt + 16384, be1, be2, nullptr,
            agg, E, tilesE);

        mlp_fused<false, false><<<dim3(gridN), dim3(NT), 0, stream>>>(
            x, agg, nullptr, nullptr, nullptr, wt + 2 * 16384, wt + 3 * 16384,
            bu1, bu2, eps, (float*)d_out, Nn, tilesN);
    } else {
        _Float16* wt = (_Float16*)((char*)d_ws + aggB);
        (void)hipMemsetAsync(agg, 0, aggB, stream);
        prep_weights<<<dim3(256), dim3(256), 0, stream>>>(We1, We2, Wu1, Wu2, wt);

        mlp_fused<true, false><<<dim3(gridE), dim3(NT), 0, stream>>>(
            x, ea, ei, ei + E, nullptr, wt, wt + 16384, be1, be2, nullptr,
            agg, E, tilesE);

        mlp_fused<false, false><<<dim3(gridN), dim3(NT), 0, stream>>>(
            x, agg, nullptr, nullptr, nullptr, wt + 2 * 16384, wt + 3 * 16384,
            bu1, bu2, eps, (float*)d_out, Nn, tilesN);
    }
}

// Round 9
// 747.043 us; speedup vs baseline: 1.0195x; 1.0195x over previous
//
#include <hip/hip_runtime.h>
#include <hip/hip_bf16.h>
#include <cstdint>

#define ND 128
#define ROWS 64
#define NT 512
#define LDA 136   // padded LDS row stride (f16 elems)
#define LDM 130   // padded LDS row stride for f32 message tile

typedef _Float16 f16x8 __attribute__((ext_vector_type(8)));
typedef float    f32x4 __attribute__((ext_vector_type(4)));

// tanh-approx GELU: gelu(v) = v*e/(e+1), e = exp2(2.302118131*v*(1+0.044715 v^2))
__device__ __forceinline__ float gelu_fast(float v) {
    float w = v * v;
    float u = v * fmaf(w, 0.044715f, 1.0f);
    float t = fminf(u * 2.302118131f, 126.0f);   // clamp: avoid inf/inf -> NaN
    float e = __builtin_amdgcn_exp2f(t);
    return v * e * __builtin_amdgcn_rcpf(e + 1.0f);
}

__device__ __forceinline__ uint32_t pkrtz_u32(float a, float b) {
    return __builtin_bit_cast(uint32_t, __builtin_amdgcn_cvt_pkrtz(a, b));
}

// Transpose + cast the four 128x128 f32 weight matrices to f16 Wt[col][k].
__global__ void prep_weights(const float* __restrict__ w0, const float* __restrict__ w1,
                             const float* __restrict__ w2, const float* __restrict__ w3,
                             _Float16* __restrict__ wt) {
    int id = blockIdx.x * blockDim.x + threadIdx.x;   // 0..65535
    int m   = id >> 14;
    int idx = id & 16383;
    int c = idx >> 7, k = idx & 127;
    const float* W = (m == 0) ? w0 : (m == 1) ? w1 : (m == 2) ? w2 : w3;
    wt[(m << 14) + (c << 7) + k] = (_Float16)W[(k << 7) + c];
}

__global__ void hist_kernel(const int* __restrict__ dst, int* __restrict__ cnt, int E) {
    int e = blockIdx.x * blockDim.x + threadIdx.x;
    if (e < E) atomicAdd(&cnt[dst[e]], 1);
}

// pass 1: per-1024-chunk exclusive scan (in place) + chunk totals
__global__ void scan_pass1(int* __restrict__ data, int* __restrict__ bsum, int n) {
    __shared__ int wsum[16];
    const int t = threadIdx.x, lane = t & 63, wv = t >> 6;
    int i = blockIdx.x * 1024 + t;
    int v = (i < n) ? data[i] : 0;
    int s = v;
    #pragma unroll
    for (int off = 1; off < 64; off <<= 1) {
        int u = __shfl_up(s, off, 64);
        if (lane >= off) s += u;
    }
    if (lane == 63) wsum[wv] = s;
    __syncthreads();
    if (t == 0) {
        int run = 0;
        #pragma unroll
        for (int w = 0; w < 16; ++w) { int x = wsum[w]; wsum[w] = run; run += x; }
        bsum[blockIdx.x] = run;
    }
    __syncthreads();
    if (i < n) data[i] = s - v + wsum[wv];
}

// pass 2: exclusive scan of chunk totals (1 block, nb <= 1024)
__global__ void scan_pass2(int* __restrict__ bsum, int nb) {
    __shared__ int wsum[16];
    const int t = threadIdx.x, lane = t & 63, wv = t >> 6;
    int v = (t < nb) ? bsum[t] : 0;
    int s = v;
    #pragma unroll
    for (int off = 1; off < 64; off <<= 1) {
        int u = __shfl_up(s, off, 64);
        if (lane >= off) s += u;
    }
    if (lane == 63) wsum[wv] = s;
    __syncthreads();
    if (t == 0) {
        int run = 0;
        #pragma unroll
        for (int w = 0; w < 16; ++w) { int x = wsum[w]; wsum[w] = run; run += x; }
    }
    __syncthreads();
    if (t < nb) bsum[t] = s - v + wsum[wv];
}

// pass 3: add chunk offsets
__global__ void scan_pass3(int* __restrict__ data, const int* __restrict__ bsum, int n) {
    int i = blockIdx.x * 1024 + threadIdx.x;
    if (i < n && blockIdx.x > 0) data[i] += bsum[blockIdx.x];
}

__global__ void scatter_kernel(const int* __restrict__ dst, int* __restrict__ cur,
                               int* __restrict__ perm, int E) {
    int e = blockIdx.x * blockDim.x + threadIdx.x;
    if (e < E) {
        int p = atomicAdd(&cur[dst[e]], 1);
        perm[p] = e;
    }
}

// Fused row-MLP with software-pipelined gather (T14 async-STAGE):
//   iter t: write A(t) from regs | S1 | load perm(t+1) | GEMM1 (+W2 frag loads)
//           | resolve src/dst(t+1) | S2 | GEMM2 | issue row loads(t+1)
//           | reduce/store path
template<bool EDGE, bool SORTED>
__global__ __launch_bounds__(NT, 4) void mlp_fused(
    const float* __restrict__ xp,
    const float* __restrict__ rowin,     // EDGE: edge_attr ; else agg
    const int*   __restrict__ srcp,
    const int*   __restrict__ dstp,
    const int*   __restrict__ permp,
    const _Float16* __restrict__ wt1,    // [128 cols][128 k] f16 (transposed)
    const _Float16* __restrict__ wt2,
    const float* __restrict__ b1p,
    const float* __restrict__ b2p,
    const float* __restrict__ epsp,
    float* __restrict__ outp,            // EDGE: agg (atomic) ; else out
    int nRows, int nTiles)
{
    // A (17408 B) | H (17408 B); M (33280 B f32) aliases A+H (SORTED only)
    __shared__ __align__(16) char lds_raw[ROWS * LDA * 2 * sizeof(_Float16)];
    __shared__ int dtile[ROWS];
    _Float16* Abuf = (_Float16*)lds_raw;
    _Float16* Hbuf = (_Float16*)(lds_raw + ROWS * LDA * sizeof(_Float16));
    float*    Mbuf = (float*)lds_raw;

    const int tid  = threadIdx.x;
    const int lane = tid & 63;
    const int wid  = tid >> 6;   // 8 waves
    const int wr   = wid >> 2;   // 0..1 : 32-row group
    const int wc   = wid & 3;    // 0..3 : 32-col group
    const int l15  = lane & 15;
    const int khi  = lane >> 4;  // 0..3

    // persistent W1 fragments only (32 VGPR); W2 reloaded per tile (L2-hot)
    f16x8 wf1[2][4];
    float bb1[2], bb2[2];
    #pragma unroll
    for (int ct = 0; ct < 2; ++ct) {
        int col = wc * 32 + ct * 16 + l15;
        #pragma unroll
        for (int kk = 0; kk < 4; ++kk)
            wf1[ct][kk] = *(const f16x8*)(wt1 + col * ND + kk * 32 + khi * 8);
        bb1[ct] = b1p[col];
        bb2[ct] = b2p[col];
    }

    float scale = 1.0f;
    if (!EDGE) scale = 1.0f + epsp[0];

    const int sr = tid >> 3;        // staging row 0..63
    const int sc = (tid & 7) * 4;   // staging col base; +i*32 per iter
    const int G  = gridDim.x;

    // ---- prefetch state for current tile ----
    float4 pa[4], pb[4];
    int  pdst = -1;
    bool pvalid;
    {
        int t = blockIdx.x;
        int grow = t * ROWS + sr;
        pvalid = (t < nTiles) && (grow < nRows);
        int prow = grow;
        if (EDGE && SORTED) prow = pvalid ? permp[grow] : 0;
        if (EDGE && SORTED) pdst = pvalid ? dstp[prow] : -1;
        if (pvalid) {
            const float* er = rowin + (size_t)prow * ND;
            const float* xr;
            if (EDGE) xr = xp + (size_t)srcp[prow] * ND;
            else      xr = xp + (size_t)grow * ND;
            #pragma unroll
            for (int i = 0; i < 4; ++i) {
                pa[i] = *(const float4*)(er + sc + i * 32);
                pb[i] = *(const float4*)(xr + sc + i * 32);
            }
        }
    }

    for (int tile = blockIdx.x; tile < nTiles; tile += G) {
        const int base = tile * ROWS;

        // ---- A-write from prefetched regs ----
        if (EDGE && SORTED && (tid & 7) == 0) dtile[sr] = pvalid ? pdst : -1;
        if (pvalid) {
            #pragma unroll
            for (int i = 0; i < 4; ++i) {
                float s0, s1, s2, s3;
                if (EDGE) {
                    s0 = pa[i].x + pb[i].x; s1 = pa[i].y + pb[i].y;
                    s2 = pa[i].z + pb[i].z; s3 = pa[i].w + pb[i].w;
                } else {
                    s0 = fmaf(scale, pb[i].x, pa[i].x); s1 = fmaf(scale, pb[i].y, pa[i].y);
                    s2 = fmaf(scale, pb[i].z, pa[i].z); s3 = fmaf(scale, pb[i].w, pa[i].w);
                }
                uint2 v;
                v.x = pkrtz_u32(s0, s1);
                v.y = pkrtz_u32(s2, s3);
                *(uint2*)&Abuf[sr * LDA + sc + i * 32] = v;
            }
        } else {
            #pragma unroll
            for (int i = 0; i < 4; ++i) {
                uint2 z = {0u, 0u};
                *(uint2*)&Abuf[sr * LDA + sc + i * 32] = z;
            }
        }

        __syncthreads();   // S1: Abuf+dtile ready; prev tile LDS readers done

        // ---- prefetch stage 1: next tile's perm index (hides under GEMM1) ----
        const int tn = tile + G;
        const int grown = tn * ROWS + sr;
        const bool nvalid = (tn < nTiles) && (grown < nRows);
        int prown = grown;
        if (EDGE && SORTED) prown = nvalid ? permp[grown] : 0;

        // W2 fragments for this tile (transient; L2-resident, overlaps GEMM1)
        f16x8 wf2[2][4];
        #pragma unroll
        for (int ct = 0; ct < 2; ++ct) {
            int col = wc * 32 + ct * 16 + l15;
            #pragma unroll
            for (int kk = 0; kk < 4; ++kk)
                wf2[ct][kk] = *(const f16x8*)(wt2 + col * ND + kk * 32 + khi * 8);
        }

        // ---- GEMM1: h = A @ W1 ----
        f32x4 acc[2][2];
        #pragma unroll
        for (int rt = 0; rt < 2; ++rt)
            #pragma unroll
            for (int ct = 0; ct < 2; ++ct)
                acc[rt][ct] = (f32x4)0.0f;

        #pragma unroll
        for (int kk = 0; kk < 4; ++kk) {
            f16x8 af[2];
            #pragma unroll
            for (int rt = 0; rt < 2; ++rt)
                af[rt] = *(const f16x8*)&Abuf[(wr * 32 + rt * 16 + l15) * LDA + kk * 32 + khi * 8];
            #pragma unroll
            for (int rt = 0; rt < 2; ++rt)
                #pragma unroll
                for (int ct = 0; ct < 2; ++ct)
                    acc[rt][ct] = __builtin_amdgcn_mfma_f32_16x16x32_f16(
                        af[rt], wf1[ct][kk], acc[rt][ct], 0, 0, 0);
        }

        // ---- prefetch stage 2: next tile's src/dst (hides under epilogue1) ----
        int ndst = -1;
        int nsrc = 0;
        if (EDGE && SORTED) ndst = nvalid ? dstp[prown] : -1;
        if (EDGE) nsrc = nvalid ? srcp[prown] : 0;

        // ---- epilogue 1: bias + GELU -> Hbuf (f16) ----
        #pragma unroll
        for (int rt = 0; rt < 2; ++rt)
            #pragma unroll
            for (int ct = 0; ct < 2; ++ct) {
                int col = wc * 32 + ct * 16 + l15;
                #pragma unroll
                for (int q = 0; q < 4; ++q) {
                    int rl = wr * 32 + rt * 16 + khi * 4 + q;
                    Hbuf[rl * LDA + col] = (_Float16)gelu_fast(acc[rt][ct][q] + bb1[ct]);
                }
            }

        __syncthreads();   // S2: Hbuf ready; Abuf GEMM1-readers done

        // ---- GEMM2: m = H @ W2 (reuse acc registers) ----
        #pragma unroll
        for (int rt = 0; rt < 2; ++rt)
            #pragma unroll
            for (int ct = 0; ct < 2; ++ct)
                acc[rt][ct] = (f32x4)0.0f;

        #pragma unroll
        for (int kk = 0; kk < 4; ++kk) {
            f16x8 hf[2];
            #pragma unroll
            for (int rt = 0; rt < 2; ++rt)
                hf[rt] = *(const f16x8*)&Hbuf[(wr * 32 + rt * 16 + l15) * LDA + kk * 32 + khi * 8];
            #pragma unroll
            for (int rt = 0; rt < 2; ++rt)
                #pragma unroll
                for (int ct = 0; ct < 2; ++ct)
                    acc[rt][ct] = __builtin_amdgcn_mfma_f32_16x16x32_f16(
                        hf[rt], wf2[ct][kk], acc[rt][ct], 0, 0, 0);
        }

        // ---- prefetch stage 3: issue next tile's row loads (hide under reduce) ----
        if (nvalid) {
            const float* ern = rowin + (size_t)prown * ND;
            const float* xrn;
            if (EDGE) xrn = xp + (size_t)nsrc * ND;
            else      xrn = xp + (size_t)grown * ND;
            #pragma unroll
            for (int i = 0; i < 4; ++i) {
                pa[i] = *(const float4*)(ern + sc + i * 32);
                pb[i] = *(const float4*)(xrn + sc + i * 32);
            }
        }
        pdst = ndst;
        pvalid = nvalid;

        if (EDGE && SORTED) {
            __syncthreads();   // S3: Hbuf reads done before Mbuf (alias) writes

            // ---- epilogue 2s: bias -> Mbuf (f32) ----
            #pragma unroll
            for (int rt = 0; rt < 2; ++rt)
                #pragma unroll
                for (int ct = 0; ct < 2; ++ct) {
                    int col = wc * 32 + ct * 16 + l15;
                    #pragma unroll
                    for (int q = 0; q < 4; ++q) {
                        int rl = wr * 32 + rt * 16 + khi * 4 + q;
                        Mbuf[rl * LDM + col] = acc[rt][ct][q] + bb2[ct];
                    }
                }

            __syncthreads();   // S4: Mbuf ready

            // ---- segmented reduce over dst-sorted rows ----
            const int rc = tid & 127;   // column
            const int rg = tid >> 7;    // 0..3 : 16-row group
            float a = 0.0f;
            #pragma unroll
            for (int r = rg * 16; r < rg * 16 + 16; ++r) {
                int d = dtile[r];
                if (d >= 0) {
                    a += Mbuf[r * LDM + rc];
                    if (r == rg * 16 + 15 || dtile[r + 1] != d) {
                        atomicAdd(outp + (size_t)d * ND + rc, a);
                        a = 0.0f;
                    }
                }
            }

            __syncthreads();   // S5: Mbuf/dtile reads done before next A-write
        } else {
            // ---- epilogue 2: bias + scatter(atomic) or store ----
            #pragma unroll
            for (int rt = 0; rt < 2; ++rt)
                #pragma unroll
                for (int ct = 0; ct < 2; ++ct) {
                    int col = wc * 32 + ct * 16 + l15;
                    #pragma unroll
                    for (int q = 0; q < 4; ++q) {
                        int rl = wr * 32 + rt * 16 + khi * 4 + q;
                        int grow = base + rl;
                        if (grow < nRows) {
                            float v = acc[rt][ct][q] + bb2[ct];
                            if (EDGE) {
                                int d = dstp[grow];
                                atomicAdd(outp + (size_t)d * ND + col, v);
                            } else {
                                outp[(size_t)grow * ND + col] = v;
                            }
                        }
                    }
                }
        }
    }
}

extern "C" void kernel_launch(void* const* d_in, const int* in_sizes, int n_in,
                              void* d_out, int out_size, void* d_ws, size_t ws_size,
                              hipStream_t stream)
{
    const float* x   = (const float*)d_in[0];
    const int*   ei  = (const int*)d_in[1];    // [2,E] int32: row0=src, row1=dst
    const float* ea  = (const float*)d_in[2];
    const float* We1 = (const float*)d_in[3];
    const float* be1 = (const float*)d_in[4];
    const float* We2 = (const float*)d_in[5];
    const float* be2 = (const float*)d_in[6];
    const float* Wu1 = (const float*)d_in[7];
    const float* bu1 = (const float*)d_in[8];
    const float* Wu2 = (const float*)d_in[9];
    const float* bu2 = (const float*)d_in[10];
    const float* eps = (const float*)d_in[11];

    const int E  = in_sizes[1] / 2;    // 600000
    const int Nn = in_sizes[0] / ND;   // 50000

    const size_t aggB = (size_t)Nn * ND * sizeof(float);      // 25.6 MB
    const size_t cntB = ((size_t)Nn * sizeof(int) + 255) & ~(size_t)255;
    const size_t prmB = (size_t)E * sizeof(int);
    const size_t bsmB = 4096;
    const size_t wtB  = 4 * 16384 * sizeof(_Float16);
    const bool sorted = (ws_size >= aggB + cntB + prmB + bsmB + wtB);

    float* agg = (float*)d_ws;
    const int tilesE = (E + ROWS - 1) / ROWS;
    const int tilesN = (Nn + ROWS - 1) / ROWS;
    const int gridE  = (tilesE < 2048) ? tilesE : 2048;
    const int gridN  = (tilesN < 2048) ? tilesN : 2048;

    if (sorted) {
        int*      cnt  = (int*)((char*)d_ws + aggB);
        int*      perm = (int*)((char*)d_ws + aggB + cntB);
        int*      bsum = (int*)((char*)d_ws + aggB + cntB + prmB);
        _Float16* wt   = (_Float16*)((char*)d_ws + aggB + cntB + prmB + bsmB);

        (void)hipMemsetAsync(d_ws, 0, aggB + cntB, stream);   // zero agg + counts
        prep_weights<<<dim3(256), dim3(256), 0, stream>>>(We1, We2, Wu1, Wu2, wt);

        const int gE = (E + 511) / 512;
        const int nb = (Nn + 1023) / 1024;
        hist_kernel<<<dim3(gE), dim3(512), 0, stream>>>(ei + E, cnt, E);
        scan_pass1<<<dim3(nb), dim3(1024), 0, stream>>>(cnt, bsum, Nn);
        scan_pass2<<<dim3(1), dim3(1024), 0, stream>>>(bsum, nb);
        scan_pass3<<<dim3(nb), dim3(1024), 0, stream>>>(cnt, bsum, Nn);
        scatter_kernel<<<dim3(gE), dim3(512), 0, stream>>>(ei + E, cnt, perm, E);

        mlp_fused<true, true><<<dim3(gridE), dim3(NT), 0, stream>>>(
            x, ea, ei, ei + E, perm, wt, wt + 16384, be1, be2, nullptr,
            agg, E, tilesE);

        mlp_fused<false, false><<<dim3(gridN), dim3(NT), 0, stream>>>(
            x, agg, nullptr, nullptr, nullptr, wt + 2 * 16384, wt + 3 * 16384,
            bu1, bu2, eps, (float*)d_out, Nn, tilesN);
    } else {
        _Float16* wt = (_Float16*)((char*)d_ws + aggB);
        (void)hipMemsetAsync(agg, 0, aggB, stream);
        prep_weights<<<dim3(256), dim3(256), 0, stream>>>(We1, We2, Wu1, Wu2, wt);

        mlp_fused<true, false><<<dim3(gridE), dim3(NT), 0, stream>>>(
            x, ea, ei, ei + E, nullptr, wt, wt + 16384, be1, be2, nullptr,
            agg, E, tilesE);

        mlp_fused<false, false><<<dim3(gridN), dim3(NT), 0, stream>>>(
            x, agg, nullptr, nullptr, nullptr, wt + 2 * 16384, wt + 3 * 16384,
            bu1, bu2, eps, (float*)d_out, Nn, tilesN);
    }
}

// Round 13
// 587.558 us; speedup vs baseline: 1.2962x; 1.2714x over previous
//
#include <hip/hip_runtime.h>
#include <hip/hip_bf16.h>
#include <cstdint>

#define ND 128
#define ROWS 32   // tile rows: 17.9KB LDS -> high block residency (R8: 84% occ)
#define NT 256    // 4 waves
#define LDA 136   // padded LDS row stride (f16 elems)
#define LDM 130   // padded LDS row stride for f32 message tile

typedef _Float16 f16x8 __attribute__((ext_vector_type(8)));
typedef float    f32x4 __attribute__((ext_vector_type(4)));

// tanh-approx GELU: gelu(v) = v*e/(e+1), e = exp2(2.302118131*v*(1+0.044715 v^2))
__device__ __forceinline__ float gelu_fast(float v) {
    float w = v * v;
    float u = v * fmaf(w, 0.044715f, 1.0f);
    float t = fminf(u * 2.302118131f, 126.0f);   // clamp: avoid inf/inf -> NaN
    float e = __builtin_amdgcn_exp2f(t);
    return v * e * __builtin_amdgcn_rcpf(e + 1.0f);
}

__device__ __forceinline__ uint32_t pkrtz_u32(float a, float b) {
    return __builtin_bit_cast(uint32_t, __builtin_amdgcn_cvt_pkrtz(a, b));
}

// Transpose + cast the four 128x128 f32 weight matrices to f16 Wt[col][k].
__global__ void prep_weights(const float* __restrict__ w0, const float* __restrict__ w1,
                             const float* __restrict__ w2, const float* __restrict__ w3,
                             _Float16* __restrict__ wt) {
    int id = blockIdx.x * blockDim.x + threadIdx.x;   // 0..65535
    int m   = id >> 14;
    int idx = id & 16383;
    int c = idx >> 7, k = idx & 127;
    const float* W = (m == 0) ? w0 : (m == 1) ? w1 : (m == 2) ? w2 : w3;
    wt[(m << 14) + (c << 7) + k] = (_Float16)W[(k << 7) + c];
}

__global__ void hist_kernel(const int* __restrict__ dst, int* __restrict__ cnt, int E) {
    int e = blockIdx.x * blockDim.x + threadIdx.x;
    if (e < E) atomicAdd(&cnt[dst[e]], 1);
}

// pass 1: per-1024-chunk exclusive scan (in place) + chunk totals
__global__ void scan_pass1(int* __restrict__ data, int* __restrict__ bsum, int n) {
    __shared__ int wsum[16];
    const int t = threadIdx.x, lane = t & 63, wv = t >> 6;
    int i = blockIdx.x * 1024 + t;
    int v = (i < n) ? data[i] : 0;
    int s = v;
    #pragma unroll
    for (int off = 1; off < 64; off <<= 1) {
        int u = __shfl_up(s, off, 64);
        if (lane >= off) s += u;
    }
    if (lane == 63) wsum[wv] = s;
    __syncthreads();
    if (t == 0) {
        int run = 0;
        #pragma unroll
        for (int w = 0; w < 16; ++w) { int x = wsum[w]; wsum[w] = run; run += x; }
        bsum[blockIdx.x] = run;
    }
    __syncthreads();
    if (i < n) data[i] = s - v + wsum[wv];
}

// pass 2: exclusive scan of chunk totals (1 block, nb <= 1024)
__global__ void scan_pass2(int* __restrict__ bsum, int nb) {
    __shared__ int wsum[16];
    const int t = threadIdx.x, lane = t & 63, wv = t >> 6;
    int v = (t < nb) ? bsum[t] : 0;
    int s = v;
    #pragma unroll
    for (int off = 1; off < 64; off <<= 1) {
        int u = __shfl_up(s, off, 64);
        if (lane >= off) s += u;
    }
    if (lane == 63) wsum[wv] = s;
    __syncthreads();
    if (t == 0) {
        int run = 0;
        #pragma unroll
        for (int w = 0; w < 16; ++w) { int x = wsum[w]; wsum[w] = run; run += x; }
    }
    __syncthreads();
    if (t < nb) bsum[t] = s - v + wsum[wv];
}

// pass 3: add chunk offsets
__global__ void scan_pass3(int* __restrict__ data, const int* __restrict__ bsum, int n) {
    int i = blockIdx.x * 1024 + threadIdx.x;
    if (i < n && blockIdx.x > 0) data[i] += bsum[blockIdx.x];
}

// scatter + materialize sorted src/dst (cuts gather chain depth 3 -> 2)
__global__ void scatter_kernel(const int* __restrict__ src, const int* __restrict__ dst,
                               int* __restrict__ cur, int* __restrict__ perm,
                               int* __restrict__ srcs, int* __restrict__ dsts, int E) {
    int e = blockIdx.x * blockDim.x + threadIdx.x;
    if (e < E) {
        int d = dst[e];
        int p = atomicAdd(&cur[d], 1);
        perm[p] = e;
        srcs[p] = src[e];
        dsts[p] = d;
    }
}

// Fused row-MLP: out_row = (GELU(in_row @ W1 + b1)) @ W2 + b2
// 256 threads = 4 waves; each wave owns 32 rows x 32 cols (2x2 16x16 frags).
template<bool EDGE, bool SORTED>
__global__ __launch_bounds__(NT, 4) void mlp_fused(   // min 4 waves/EU -> 128 VGPR cap, no spill
    const float* __restrict__ xp,
    const float* __restrict__ rowin,     // EDGE: edge_attr ; else agg
    const int*   __restrict__ srcp,      // SORTED: materialized srcs ; else raw src
    const int*   __restrict__ dstp,      // SORTED: materialized dsts ; else raw dst
    const int*   __restrict__ permp,
    const _Float16* __restrict__ wt1,    // [128 cols][128 k] f16 (transposed)
    const _Float16* __restrict__ wt2,
    const float* __restrict__ b1p,
    const float* __restrict__ b2p,
    const float* __restrict__ epsp,
    float* __restrict__ outp,            // EDGE: agg (atomic) ; else out
    int nRows, int nTiles)
{
    // A (8704 B) | H (8704 B); M (16640 B f32) aliases A+H (SORTED only)
    __shared__ __align__(16) char lds_raw[ROWS * LDA * 2 * sizeof(_Float16)];
    __shared__ int dtile[ROWS];
    _Float16* Abuf = (_Float16*)lds_raw;
    _Float16* Hbuf = (_Float16*)(lds_raw + ROWS * LDA * sizeof(_Float16));
    float*    Mbuf = (float*)lds_raw;

    const int tid  = threadIdx.x;
    const int lane = tid & 63;
    const int wc   = tid >> 6;   // 4 waves: each owns a 32-col group
    const int l15  = lane & 15;
    const int khi  = lane >> 4;  // 0..3

    // weight fragments (compiler may rematerialize from L2 per tile; either is fine)
    f16x8 wf1[2][4], wf2[2][4];
    float bb1[2], bb2[2];
    #pragma unroll
    for (int ct = 0; ct < 2; ++ct) {
        int col = wc * 32 + ct * 16 + l15;
        #pragma unroll
        for (int kk = 0; kk < 4; ++kk) {
            wf1[ct][kk] = *(const f16x8*)(wt1 + col * ND + kk * 32 + khi * 8);
            wf2[ct][kk] = *(const f16x8*)(wt2 + col * ND + kk * 32 + khi * 8);
        }
        bb1[ct] = b1p[col];
        bb2[ct] = b2p[col];
    }

    float scale = 1.0f;
    if (!EDGE) scale = 1.0f + epsp[0];

    const int sr = tid >> 3;        // staging row 0..31
    const int sc = (tid & 7) * 4;   // staging col base; +i*32 per iter

    for (int tile = blockIdx.x; tile < nTiles; tile += gridDim.x) {
        const int base = tile * ROWS;

        // ---- stage A tile (f32 -> f16 via pkrtz, fused gather/add) + dtile ----
        {
            int grow = base + sr;
            if (grow < nRows) {
                int arow = grow;   // edge_attr row (perm) — independent loads, no chain
                int xrow = grow;
                if (EDGE && SORTED) {
                    arow = permp[grow];
                    xrow = srcp[grow];        // materialized: no double indirection
                    if ((tid & 7) == 0) dtile[sr] = dstp[grow];
                } else if (EDGE) {
                    xrow = srcp[grow];
                }
                const float* er = rowin + (size_t)arow * ND;
                const float* xr = xp + (size_t)xrow * ND;
                #pragma unroll
                for (int i = 0; i < 4; ++i) {
                    int c = sc + i * 32;
                    float4 a = *(const float4*)(er + c);
                    float4 b = *(const float4*)(xr + c);
                    float s0, s1, s2, s3;
                    if (EDGE) {
                        s0 = a.x + b.x; s1 = a.y + b.y; s2 = a.z + b.z; s3 = a.w + b.w;
                    } else {
                        s0 = fmaf(scale, b.x, a.x); s1 = fmaf(scale, b.y, a.y);
                        s2 = fmaf(scale, b.z, a.z); s3 = fmaf(scale, b.w, a.w);
                    }
                    uint2 v;
                    v.x = pkrtz_u32(s0, s1);
                    v.y = pkrtz_u32(s2, s3);
                    *(uint2*)&Abuf[sr * LDA + c] = v;
                }
            } else {
                if (EDGE && SORTED && (tid & 7) == 0) dtile[sr] = -1;
                #pragma unroll
                for (int i = 0; i < 4; ++i) {
                    uint2 z = {0u, 0u};
                    *(uint2*)&Abuf[sr * LDA + sc + i * 32] = z;
                }
            }
        }

        __syncthreads();   // S1: Abuf+dtile ready; prev tile LDS readers done

        // ---- GEMM1: h = A @ W1 ----
        f32x4 acc[2][2];
        #pragma unroll
        for (int rt = 0; rt < 2; ++rt)
            #pragma unroll
            for (int ct = 0; ct < 2; ++ct)
                acc[rt][ct] = (f32x4)0.0f;

        #pragma unroll
        for (int kk = 0; kk < 4; ++kk) {
            f16x8 af[2];
            #pragma unroll
            for (int rt = 0; rt < 2; ++rt)
                af[rt] = *(const f16x8*)&Abuf[(rt * 16 + l15) * LDA + kk * 32 + khi * 8];
            #pragma unroll
            for (int rt = 0; rt < 2; ++rt)
                #pragma unroll
                for (int ct = 0; ct < 2; ++ct)
                    acc[rt][ct] = __builtin_amdgcn_mfma_f32_16x16x32_f16(
                        af[rt], wf1[ct][kk], acc[rt][ct], 0, 0, 0);
        }

        // ---- epilogue 1: bias + GELU -> Hbuf (f16) ----
        #pragma unroll
        for (int rt = 0; rt < 2; ++rt)
            #pragma unroll
            for (int ct = 0; ct < 2; ++ct) {
                int col = wc * 32 + ct * 16 + l15;
                #pragma unroll
                for (int q = 0; q < 4; ++q) {
                    int rl = rt * 16 + khi * 4 + q;
                    Hbuf[rl * LDA + col] = (_Float16)gelu_fast(acc[rt][ct][q] + bb1[ct]);
                }
            }

        __syncthreads();   // S2: Hbuf ready

        // ---- GEMM2: m = H @ W2 (reuse acc) ----
        #pragma unroll
        for (int rt = 0; rt < 2; ++rt)
            #pragma unroll
            for (int ct = 0; ct < 2; ++ct)
                acc[rt][ct] = (f32x4)0.0f;

        #pragma unroll
        for (int kk = 0; kk < 4; ++kk) {
            f16x8 hf[2];
            #pragma unroll
            for (int rt = 0; rt < 2; ++rt)
                hf[rt] = *(const f16x8*)&Hbuf[(rt * 16 + l15) * LDA + kk * 32 + khi * 8];
            #pragma unroll
            for (int rt = 0; rt < 2; ++rt)
                #pragma unroll
                for (int ct = 0; ct < 2; ++ct)
                    acc[rt][ct] = __builtin_amdgcn_mfma_f32_16x16x32_f16(
                        hf[rt], wf2[ct][kk], acc[rt][ct], 0, 0, 0);
        }

        if (EDGE && SORTED) {
            __syncthreads();   // S3: Hbuf reads done before Mbuf (alias) writes

            // ---- epilogue 2s: bias -> Mbuf (f32) ----
            #pragma unroll
            for (int rt = 0; rt < 2; ++rt)
                #pragma unroll
                for (int ct = 0; ct < 2; ++ct) {
                    int col = wc * 32 + ct * 16 + l15;
                    #pragma unroll
                    for (int q = 0; q < 4; ++q) {
                        int rl = rt * 16 + khi * 4 + q;
                        Mbuf[rl * LDM + col] = acc[rt][ct][q] + bb2[ct];
                    }
                }

            __syncthreads();   // S4: Mbuf ready

            // ---- segmented reduce over dst-sorted rows (2 groups of 16) ----
            const int rc = tid & 127;   // column
            const int rg = tid >> 7;    // 0..1 : 16-row group
            float a = 0.0f;
            #pragma unroll
            for (int r = rg * 16; r < rg * 16 + 16; ++r) {
                int d = dtile[r];
                if (d >= 0) {
                    a += Mbuf[r * LDM + rc];
                    if (r == rg * 16 + 15 || dtile[r + 1] != d) {
                        atomicAdd(outp + (size_t)d * ND + rc, a);
                        a = 0.0f;
                    }
                }
            }

            __syncthreads();   // S5: Mbuf/dtile reads done before next stage
        } else {
            // ---- epilogue 2: bias + scatter(atomic) or store ----
            #pragma unroll
            for (int rt = 0; rt < 2; ++rt)
                #pragma unroll
                for (int ct = 0; ct < 2; ++ct) {
                    int col = wc * 32 + ct * 16 + l15;
                    #pragma unroll
                    for (int q = 0; q < 4; ++q) {
                        int rl = rt * 16 + khi * 4 + q;
                        int grow = base + rl;
                        if (grow < nRows) {
                            float v = acc[rt][ct][q] + bb2[ct];
                            if (EDGE) {
                                int d = dstp[grow];
                                atomicAdd(outp + (size_t)d * ND + col, v);
                            } else {
                                outp[(size_t)grow * ND + col] = v;
                            }
                        }
                    }
                }
        }
    }
}

extern "C" void kernel_launch(void* const* d_in, const int* in_sizes, int n_in,
                              void* d_out, int out_size, void* d_ws, size_t ws_size,
                              hipStream_t stream)
{
    const float* x   = (const float*)d_in[0];
    const int*   ei  = (const int*)d_in[1];    // [2,E] int32: row0=src, row1=dst
    const float* ea  = (const float*)d_in[2];
    const float* We1 = (const float*)d_in[3];
    const float* be1 = (const float*)d_in[4];
    const float* We2 = (const float*)d_in[5];
    const float* be2 = (const float*)d_in[6];
    const float* Wu1 = (const float*)d_in[7];
    const float* bu1 = (const float*)d_in[8];
    const float* Wu2 = (const float*)d_in[9];
    const float* bu2 = (const float*)d_in[10];
    const float* eps = (const float*)d_in[11];

    const int E  = in_sizes[1] / 2;    // 600000
    const int Nn = in_sizes[0] / ND;   // 50000

    const size_t aggB = (size_t)Nn * ND * sizeof(float);      // 25.6 MB
    const size_t cntB = ((size_t)Nn * sizeof(int) + 255) & ~(size_t)255;
    const size_t prmB = (size_t)E * sizeof(int);
    const size_t bsmB = 4096;
    const size_t wtB  = 4 * 16384 * sizeof(_Float16);
    const bool sorted = (ws_size >= aggB + cntB + 3 * prmB + bsmB + wtB);

    float* agg = (float*)d_ws;
    const int tilesE = (E + ROWS - 1) / ROWS;
    const int tilesN = (Nn + ROWS - 1) / ROWS;
    const int gridE  = (tilesE < 2048) ? tilesE : 2048;
    const int gridN  = (tilesN < 2048) ? tilesN : 2048;

    if (sorted) {
        char* p = (char*)d_ws + aggB;
        int*      cnt  = (int*)p;            p += cntB;
        int*      perm = (int*)p;            p += prmB;
        int*      srcs = (int*)p;            p += prmB;
        int*      dsts = (int*)p;            p += prmB;
        int*      bsum = (int*)p;            p += bsmB;
        _Float16* wt   = (_Float16*)p;

        (void)hipMemsetAsync(d_ws, 0, aggB + cntB, stream);   // zero agg + counts
        prep_weights<<<dim3(256), dim3(256), 0, stream>>>(We1, We2, Wu1, Wu2, wt);

        const int gE = (E + 511) / 512;
        const int nb = (Nn + 1023) / 1024;
        hist_kernel<<<dim3(gE), dim3(512), 0, stream>>>(ei + E, cnt, E);
        scan_pass1<<<dim3(nb), dim3(1024), 0, stream>>>(cnt, bsum, Nn);
        scan_pass2<<<dim3(1), dim3(1024), 0, stream>>>(bsum, nb);
        scan_pass3<<<dim3(nb), dim3(1024), 0, stream>>>(cnt, bsum, Nn);
        scatter_kernel<<<dim3(gE), dim3(512), 0, stream>>>(ei, ei + E, cnt, perm, srcs, dsts, E);

        mlp_fused<true, true><<<dim3(gridE), dim3(NT), 0, stream>>>(
            x, ea, srcs, dsts, perm, wt, wt + 16384, be1, be2, nullptr,
            agg, E, tilesE);

        mlp_fused<false, false><<<dim3(gridN), dim3(NT), 0, stream>>>(
            x, agg, nullptr, nullptr, nullptr, wt + 2 * 16384, wt + 3 * 16384,
            bu1, bu2, eps, (float*)d_out, Nn, tilesN);
    } else {
        _Float16* wt = (_Float16*)((char*)d_ws + aggB);
        (void)hipMemsetAsync(agg, 0, aggB, stream);
        prep_weights<<<dim3(256), dim3(256), 0, stream>>>(We1, We2, Wu1, Wu2, wt);

        mlp_fused<true, false><<<dim3(gridE), dim3(NT), 0, stream>>>(
            x, ea, ei, ei + E, nullptr, wt, wt + 16384, be1, be2, nullptr,
            agg, E, tilesE);

        mlp_fused<false, false><<<dim3(gridN), dim3(NT), 0, stream>>>(
            x, agg, nullptr, nullptr, nullptr, wt + 2 * 16384, wt + 3 * 16384,
            bu1, bu2, eps, (float*)d_out, Nn, tilesN);
    }
}